// Round 1
// baseline (101.955 us; speedup 1.0000x reference)
//
#include <hip/hip_runtime.h>

constexpr int Bn = 2;
constexpr int Sn = 4096;
constexpr int Hh = 16;
constexpr int Dn = 64;
constexpr int HD = 1024;   // Hh * Dn
constexpr int NB = 64;     // Sn / 64
constexpr int KS = 7;      // ceil(0.1 * NB)

typedef _Float16 f16x8 __attribute__((ext_vector_type(8)));
typedef _Float16 f16x4 __attribute__((ext_vector_type(4)));
typedef float    f32x4 __attribute__((ext_vector_type(4)));

static __device__ __forceinline__ f16x4 cvt4(float4 v) {
    f16x4 r;
    r[0] = (_Float16)v.x; r[1] = (_Float16)v.y;
    r[2] = (_Float16)v.z; r[3] = (_Float16)v.w;
    return r;
}

// ---------------- kernel 1: per-block mean pooling of Q and K ----------------
__global__ __launch_bounds__(64) void sla_pool(const float* __restrict__ Q,
                                               const float* __restrict__ K,
                                               float* __restrict__ qpool,
                                               float* __restrict__ kpool) {
    int bid = blockIdx.x;                 // (b*Hh + h)*NB + nb
    int b   = bid / (Hh * NB);
    int rem = bid % (Hh * NB);
    int h   = rem / NB;
    int nb  = rem % NB;
    int d   = threadIdx.x;

    const float* qp = Q + ((size_t)b * Sn + (size_t)nb * 64) * HD + h * Dn + d;
    const float* kp = K + ((size_t)b * Sn + (size_t)nb * 64) * HD + h * Dn + d;
    double sq = 0.0, sk = 0.0;
    #pragma unroll 8
    for (int r = 0; r < 64; ++r) {
        sq += (double)qp[(size_t)r * HD];
        sk += (double)kp[(size_t)r * HD];
    }
    qpool[(size_t)bid * 64 + d] = (float)(sq * (1.0 / 64.0));
    kpool[(size_t)bid * 64 + d] = (float)(sk * (1.0 / 64.0));
}

// -------- kernel 2: block scores (fp64) + top-7 selection (lax.top_k ties: lower idx) --------
__global__ __launch_bounds__(64) void sla_topk(const float* __restrict__ qpool,
                                               const float* __restrict__ kpool,
                                               int* __restrict__ topk) {
    int bid = blockIdx.x;                 // (b*Hh + h)*NB + nb
    int bh  = bid / NB;
    int j   = threadIdx.x;                // candidate key block

    const float* qp = qpool + (size_t)bid * 64;
    const float* kp = kpool + ((size_t)bh * NB + j) * 64;
    double s = 0.0;
    #pragma unroll 8
    for (int d = 0; d < 64; ++d) s += (double)qp[d] * (double)kp[d];

    double v  = s;
    int   idx = j;
    #pragma unroll
    for (int it = 0; it < KS; ++it) {
        double bv = v; int bi = idx;
        #pragma unroll
        for (int off = 1; off < 64; off <<= 1) {
            double ov = __shfl_xor(bv, off);
            int    oi = __shfl_xor(bi, off);
            if (ov > bv || (ov == bv && oi < bi)) { bv = ov; bi = oi; }
        }
        if (j == 0) topk[(size_t)bid * KS + it] = bi;
        if (idx == bi) v = -1e300;        // knock out the winner
    }
}

// ---------------- kernel 3: sparse flash attention over selected blocks ----------------
__global__ __launch_bounds__(256) void sla_attn(const float* __restrict__ Q,
                                                const float* __restrict__ K,
                                                const float* __restrict__ V,
                                                const int* __restrict__ topk,
                                                float* __restrict__ O) {
    __shared__ _Float16 Ks[64][72];       // [key][d]   (stride 144 B, 16B-aligned rows)
    __shared__ _Float16 Vt[64][72];       // [d][key]   transposed for PV B-fragment
    __shared__ _Float16 Pl[4][16][72];    // per-wave P tile [q][key]

    int bid = blockIdx.x;
    int b   = bid / (Hh * NB);
    int rem = bid % (Hh * NB);
    int h   = rem / NB;
    int nb  = rem % NB;

    int tid  = threadIdx.x;
    int w    = tid >> 6;                  // wave id: rows [w*16, w*16+16)
    int lane = tid & 63;
    int c    = lane & 15;                 // frag col / A-row index
    int g    = lane >> 4;                 // frag k-group

    int skey = tid >> 2;                  // staging: key row
    int sdg  = (tid & 3) << 4;            // staging: d-group of 16

    // ---- Q fragments, scale 1/8 folded (exact in fp16) ----
    f16x8 qf[2];
    {
        const float* qrow = Q + ((size_t)b * Sn + (size_t)nb * 64 + w * 16 + c) * HD + h * Dn;
        #pragma unroll
        for (int s2 = 0; s2 < 2; ++s2) {
            float4 a0 = *(const float4*)(qrow + s2 * 32 + g * 8);
            float4 a1 = *(const float4*)(qrow + s2 * 32 + g * 8 + 4);
            f16x8 q;
            q[0] = (_Float16)(a0.x * 0.125f); q[1] = (_Float16)(a0.y * 0.125f);
            q[2] = (_Float16)(a0.z * 0.125f); q[3] = (_Float16)(a0.w * 0.125f);
            q[4] = (_Float16)(a1.x * 0.125f); q[5] = (_Float16)(a1.y * 0.125f);
            q[6] = (_Float16)(a1.z * 0.125f); q[7] = (_Float16)(a1.w * 0.125f);
            qf[s2] = q;
        }
    }

    float m[4], l[4];
    f32x4 oacc[4];
    #pragma unroll
    for (int r = 0; r < 4; ++r) { m[r] = -1e30f; l[r] = 0.f; }
    #pragma unroll
    for (int t = 0; t < 4; ++t) oacc[t] = f32x4{0.f, 0.f, 0.f, 0.f};

    const float* kbase = K + (size_t)b * Sn * HD + h * Dn;
    const float* vbase = V + (size_t)b * Sn * HD + h * Dn;

    for (int kb = 0; kb < KS; ++kb) {
        int jblk = topk[(size_t)bid * KS + kb];
        __syncthreads();                  // previous iter's PV done before overwrite
        // ---- stage K_j row-major, V_j transposed ----
        {
            const float* kp = kbase + ((size_t)jblk * 64 + skey) * HD + sdg;
            float4 x0 = *(const float4*)(kp + 0);
            float4 x1 = *(const float4*)(kp + 4);
            float4 x2 = *(const float4*)(kp + 8);
            float4 x3 = *(const float4*)(kp + 12);
            *(f16x4*)&Ks[skey][sdg +  0] = cvt4(x0);
            *(f16x4*)&Ks[skey][sdg +  4] = cvt4(x1);
            *(f16x4*)&Ks[skey][sdg +  8] = cvt4(x2);
            *(f16x4*)&Ks[skey][sdg + 12] = cvt4(x3);

            const float* vp = vbase + ((size_t)jblk * 64 + skey) * HD + sdg;
            float yv[16];
            *(float4*)&yv[0]  = *(const float4*)(vp + 0);
            *(float4*)&yv[4]  = *(const float4*)(vp + 4);
            *(float4*)&yv[8]  = *(const float4*)(vp + 8);
            *(float4*)&yv[12] = *(const float4*)(vp + 12);
            #pragma unroll
            for (int i = 0; i < 16; ++i)
                Vt[sdg + i][skey] = (_Float16)yv[i];
        }
        __syncthreads();

        // ---- S = (Q/8) K^T : C-layout col=key(lane&15 +16t), row=q((lane>>4)*4+reg) ----
        f32x4 sacc[4];
        #pragma unroll
        for (int t = 0; t < 4; ++t) sacc[t] = f32x4{0.f, 0.f, 0.f, 0.f};
        #pragma unroll
        for (int t = 0; t < 4; ++t) {
            #pragma unroll
            for (int s2 = 0; s2 < 2; ++s2) {
                f16x8 bf = *(const f16x8*)&Ks[t * 16 + c][s2 * 32 + g * 8];
                sacc[t] = __builtin_amdgcn_mfma_f32_16x16x32_f16(qf[s2], bf, sacc[t], 0, 0, 0);
            }
        }

        // ---- online softmax (rows live on 16-lane groups; reduce over lane&15) ----
        float pm[4];
        #pragma unroll
        for (int r = 0; r < 4; ++r)
            pm[r] = fmaxf(fmaxf(sacc[0][r], sacc[1][r]), fmaxf(sacc[2][r], sacc[3][r]));
        #pragma unroll
        for (int off = 1; off < 16; off <<= 1) {
            #pragma unroll
            for (int r = 0; r < 4; ++r)
                pm[r] = fmaxf(pm[r], __shfl_xor(pm[r], off));
        }
        float al[4], rs[4], pv[4][4];
        #pragma unroll
        for (int r = 0; r < 4; ++r) {
            float mn = fmaxf(m[r], pm[r]);
            al[r] = __expf(m[r] - mn);
            m[r]  = mn;
            rs[r] = 0.f;
        }
        #pragma unroll
        for (int t = 0; t < 4; ++t) {
            #pragma unroll
            for (int r = 0; r < 4; ++r) {
                float e = __expf(sacc[t][r] - m[r]);
                pv[t][r] = e;
                rs[r] += e;
            }
        }
        #pragma unroll
        for (int off = 1; off < 16; off <<= 1) {
            #pragma unroll
            for (int r = 0; r < 4; ++r)
                rs[r] += __shfl_xor(rs[r], off);
        }
        #pragma unroll
        for (int r = 0; r < 4; ++r) l[r] = l[r] * al[r] + rs[r];
        #pragma unroll
        for (int t = 0; t < 4; ++t) {
            #pragma unroll
            for (int r = 0; r < 4; ++r) oacc[t][r] *= al[r];
        }

        // ---- P -> LDS (re-layout C-frag -> A-frag) ----
        #pragma unroll
        for (int t = 0; t < 4; ++t) {
            #pragma unroll
            for (int r = 0; r < 4; ++r)
                Pl[w][g * 4 + r][t * 16 + c] = (_Float16)pv[t][r];
        }
        __syncthreads();

        // ---- O += P V ----
        f16x8 af0 = *(const f16x8*)&Pl[w][c][g * 8];
        f16x8 af1 = *(const f16x8*)&Pl[w][c][32 + g * 8];
        #pragma unroll
        for (int t = 0; t < 4; ++t) {
            f16x8 b0 = *(const f16x8*)&Vt[t * 16 + c][g * 8];
            f16x8 b1 = *(const f16x8*)&Vt[t * 16 + c][32 + g * 8];
            oacc[t] = __builtin_amdgcn_mfma_f32_16x16x32_f16(af0, b0, oacc[t], 0, 0, 0);
            oacc[t] = __builtin_amdgcn_mfma_f32_16x16x32_f16(af1, b1, oacc[t], 0, 0, 0);
        }
    }

    // ---- epilogue: O / l ----
    float* orow = O + ((size_t)b * Sn + (size_t)nb * 64 + w * 16) * HD + h * Dn;
    #pragma unroll
    for (int r = 0; r < 4; ++r) {
        float inv = 1.0f / l[r];
        #pragma unroll
        for (int t = 0; t < 4; ++t)
            orow[(size_t)(g * 4 + r) * HD + t * 16 + c] = oacc[t][r] * inv;
    }
}

extern "C" void kernel_launch(void* const* d_in, const int* in_sizes, int n_in,
                              void* d_out, int out_size, void* d_ws, size_t ws_size,
                              hipStream_t stream) {
    const float* Q = (const float*)d_in[0];
    const float* K = (const float*)d_in[1];
    const float* V = (const float*)d_in[2];
    float* O = (float*)d_out;

    float* qpool = (float*)d_ws;                      // 131072 f32
    float* kpool = qpool + (size_t)Bn * Hh * NB * Dn; // 131072 f32
    int*   topk  = (int*)(kpool + (size_t)Bn * Hh * NB * Dn); // 2048*7 int

    dim3 grid(Bn * Hh * NB);
    sla_pool<<<grid, 64, 0, stream>>>(Q, K, qpool, kpool);
    sla_topk<<<grid, 64, 0, stream>>>(qpool, kpool, topk);
    sla_attn<<<grid, 256, 0, stream>>>(Q, K, V, topk, O);
}

// Round 2
// 88.320 us; speedup vs baseline: 1.1544x; 1.1544x over previous
//
#include <hip/hip_runtime.h>

constexpr int Bn = 2;
constexpr int Sn = 4096;
constexpr int Hh = 16;
constexpr int Dn = 64;
constexpr int HD = 1024;   // Hh * Dn
constexpr int NB = 64;     // Sn / 64
constexpr int KS = 7;      // ceil(0.1 * NB)

typedef _Float16 f16x8 __attribute__((ext_vector_type(8)));
typedef _Float16 f16x4 __attribute__((ext_vector_type(4)));
typedef float    f32x4 __attribute__((ext_vector_type(4)));

static __device__ __forceinline__ f16x4 cvt4(float4 v) {
    f16x4 r;
    r[0] = (_Float16)v.x; r[1] = (_Float16)v.y;
    r[2] = (_Float16)v.z; r[3] = (_Float16)v.w;
    return r;
}

// ---------------- kernel 1: per-block mean pooling of Q and K ----------------
__global__ __launch_bounds__(64) void sla_pool(const float* __restrict__ Q,
                                               const float* __restrict__ K,
                                               float* __restrict__ qpool,
                                               float* __restrict__ kpool) {
    int bid = blockIdx.x;                 // (b*Hh + h)*NB + nb
    int b   = bid / (Hh * NB);
    int rem = bid % (Hh * NB);
    int h   = rem / NB;
    int nb  = rem % NB;
    int d   = threadIdx.x;

    const float* qp = Q + ((size_t)b * Sn + (size_t)nb * 64) * HD + h * Dn + d;
    const float* kp = K + ((size_t)b * Sn + (size_t)nb * 64) * HD + h * Dn + d;
    double sq = 0.0, sk = 0.0;
    #pragma unroll 16
    for (int r = 0; r < 64; ++r) {
        sq += (double)qp[(size_t)r * HD];
        sk += (double)kp[(size_t)r * HD];
    }
    qpool[(size_t)bid * 64 + d] = (float)(sq * (1.0 / 64.0));
    kpool[(size_t)bid * 64 + d] = (float)(sk * (1.0 / 64.0));
}

// -------- kernel 2: block scores (fp64) + top-7 selection (lax.top_k ties: lower idx) --------
__global__ __launch_bounds__(64) void sla_topk(const float* __restrict__ qpool,
                                               const float* __restrict__ kpool,
                                               int* __restrict__ topk) {
    int bid = blockIdx.x;                 // (b*Hh + h)*NB + nb
    int bh  = bid / NB;
    int j   = threadIdx.x;                // candidate key block

    const float* qp = qpool + (size_t)bid * 64;
    const float* kp = kpool + ((size_t)bh * NB + j) * 64;
    double s = 0.0;
    #pragma unroll 8
    for (int d = 0; d < 64; ++d) s += (double)qp[d] * (double)kp[d];

    double v  = s;
    int   idx = j;
    #pragma unroll
    for (int it = 0; it < KS; ++it) {
        double bv = v; int bi = idx;
        #pragma unroll
        for (int off = 1; off < 64; off <<= 1) {
            double ov = __shfl_xor(bv, off);
            int    oi = __shfl_xor(bi, off);
            if (ov > bv || (ov == bv && oi < bi)) { bv = ov; bi = oi; }
        }
        if (j == 0) topk[(size_t)bid * KS + it] = bi;
        if (idx == bi) v = -1e300;        // knock out the winner
    }
}

// ---------------- kernel 3: sparse flash attention over selected blocks ----------------
__global__ __launch_bounds__(256) void sla_attn(const float* __restrict__ Q,
                                                const float* __restrict__ K,
                                                const float* __restrict__ V,
                                                const int* __restrict__ topk,
                                                float* __restrict__ O) {
    __shared__ _Float16 Ks[64][72];       // [key][d]   (stride 144 B, 16B-aligned rows)
    __shared__ _Float16 Vt[64][72];       // [d][key^swz] transposed + XOR-swizzled cols
    __shared__ _Float16 Pl[4][16][72];    // per-wave P tile [q][key]

    // XCD-chunked swizzle: 2048 WGs = 8 XCDs x 256; consecutive logical bids
    // (same b,h -> shared K/V working set, ~2MB < 4MB XCD L2) stay on one XCD.
    int raw = blockIdx.x;
    int bid = (raw & 7) * 256 + (raw >> 3);

    int b   = bid / (Hh * NB);
    int rem = bid % (Hh * NB);
    int h   = rem / NB;
    int nb  = rem % NB;

    int tid  = threadIdx.x;
    int w    = tid >> 6;                  // wave id: rows [w*16, w*16+16)
    int lane = tid & 63;
    int c    = lane & 15;                 // frag col / A-row index
    int g    = lane >> 4;                 // frag k-group

    int skey = tid >> 2;                  // staging: key row
    int sdg  = (tid & 3) << 4;            // staging: d-group of 16
    int vcol = skey ^ ((tid & 3) << 4);   // Vt swizzled write column (per-thread const)

    // ---- hoist all 7 selected block indices (uniform -> scalar loads) ----
    int jidx[KS];
    {
        const int* tkp = topk + (size_t)bid * KS;
        #pragma unroll
        for (int i = 0; i < KS; ++i) jidx[i] = tkp[i];
    }

    // ---- Q fragments, scale 1/8 folded (exact in fp16) ----
    f16x8 qf[2];
    {
        const float* qrow = Q + ((size_t)b * Sn + (size_t)nb * 64 + w * 16 + c) * HD + h * Dn;
        #pragma unroll
        for (int s2 = 0; s2 < 2; ++s2) {
            float4 a0 = *(const float4*)(qrow + s2 * 32 + g * 8);
            float4 a1 = *(const float4*)(qrow + s2 * 32 + g * 8 + 4);
            f16x8 q;
            q[0] = (_Float16)(a0.x * 0.125f); q[1] = (_Float16)(a0.y * 0.125f);
            q[2] = (_Float16)(a0.z * 0.125f); q[3] = (_Float16)(a0.w * 0.125f);
            q[4] = (_Float16)(a1.x * 0.125f); q[5] = (_Float16)(a1.y * 0.125f);
            q[6] = (_Float16)(a1.z * 0.125f); q[7] = (_Float16)(a1.w * 0.125f);
            qf[s2] = q;
        }
    }

    float m[4], l[4];
    f32x4 oacc[4];
    #pragma unroll
    for (int r = 0; r < 4; ++r) { m[r] = -1e30f; l[r] = 0.f; }
    #pragma unroll
    for (int t = 0; t < 4; ++t) oacc[t] = f32x4{0.f, 0.f, 0.f, 0.f};

    const float* kbase = K + (size_t)b * Sn * HD + h * Dn;
    const float* vbase = V + (size_t)b * Sn * HD + h * Dn;

    // ---- prologue: prefetch block 0 into registers ----
    float4 kx[4], vx[4];
    {
        const float* kp = kbase + ((size_t)jidx[0] * 64 + skey) * HD + sdg;
        const float* vp = vbase + ((size_t)jidx[0] * 64 + skey) * HD + sdg;
        #pragma unroll
        for (int i = 0; i < 4; ++i) kx[i] = *(const float4*)(kp + i * 4);
        #pragma unroll
        for (int i = 0; i < 4; ++i) vx[i] = *(const float4*)(vp + i * 4);
    }

    for (int kb = 0; kb < KS; ++kb) {
        __syncthreads();                  // previous iter's MFMA reads of Ks/Vt done
        // ---- STAGE_WRITE: regs -> LDS (cvt to f16; Vt transposed + swizzled) ----
        #pragma unroll
        for (int i = 0; i < 4; ++i)
            *(f16x4*)&Ks[skey][sdg + i * 4] = cvt4(kx[i]);
        #pragma unroll
        for (int i = 0; i < 4; ++i) {
            float4 v = vx[i];
            int db = sdg + i * 4;
            Vt[db + 0][vcol] = (_Float16)v.x;
            Vt[db + 1][vcol] = (_Float16)v.y;
            Vt[db + 2][vcol] = (_Float16)v.z;
            Vt[db + 3][vcol] = (_Float16)v.w;
        }
        // ---- PREFETCH next block into registers (overlaps barrier + compute) ----
        if (kb + 1 < KS) {
            const float* kp = kbase + ((size_t)jidx[kb + 1] * 64 + skey) * HD + sdg;
            const float* vp = vbase + ((size_t)jidx[kb + 1] * 64 + skey) * HD + sdg;
            #pragma unroll
            for (int i = 0; i < 4; ++i) kx[i] = *(const float4*)(kp + i * 4);
            #pragma unroll
            for (int i = 0; i < 4; ++i) vx[i] = *(const float4*)(vp + i * 4);
        }
        __syncthreads();                  // staging visible to all waves

        // ---- S = (Q/8) K^T : C-layout col=key(lane&15 +16t), row=q((lane>>4)*4+reg) ----
        f32x4 sacc[4];
        #pragma unroll
        for (int t = 0; t < 4; ++t) sacc[t] = f32x4{0.f, 0.f, 0.f, 0.f};
        #pragma unroll
        for (int t = 0; t < 4; ++t) {
            #pragma unroll
            for (int s2 = 0; s2 < 2; ++s2) {
                f16x8 bf = *(const f16x8*)&Ks[t * 16 + c][s2 * 32 + g * 8];
                sacc[t] = __builtin_amdgcn_mfma_f32_16x16x32_f16(qf[s2], bf, sacc[t], 0, 0, 0);
            }
        }

        // ---- online softmax (rows live on 16-lane groups; reduce over lane&15) ----
        float pm[4];
        #pragma unroll
        for (int r = 0; r < 4; ++r)
            pm[r] = fmaxf(fmaxf(sacc[0][r], sacc[1][r]), fmaxf(sacc[2][r], sacc[3][r]));
        #pragma unroll
        for (int off = 1; off < 16; off <<= 1) {
            #pragma unroll
            for (int r = 0; r < 4; ++r)
                pm[r] = fmaxf(pm[r], __shfl_xor(pm[r], off));
        }
        float al[4], rs[4], pv[4][4];
        #pragma unroll
        for (int r = 0; r < 4; ++r) {
            float mn = fmaxf(m[r], pm[r]);
            al[r] = __expf(m[r] - mn);
            m[r]  = mn;
            rs[r] = 0.f;
        }
        #pragma unroll
        for (int t = 0; t < 4; ++t) {
            #pragma unroll
            for (int r = 0; r < 4; ++r) {
                float e = __expf(sacc[t][r] - m[r]);
                pv[t][r] = e;
                rs[r] += e;
            }
        }
        #pragma unroll
        for (int off = 1; off < 16; off <<= 1) {
            #pragma unroll
            for (int r = 0; r < 4; ++r)
                rs[r] += __shfl_xor(rs[r], off);
        }
        #pragma unroll
        for (int r = 0; r < 4; ++r) l[r] = l[r] * al[r] + rs[r];
        #pragma unroll
        for (int t = 0; t < 4; ++t) {
            #pragma unroll
            for (int r = 0; r < 4; ++r) oacc[t][r] *= al[r];
        }

        // ---- P -> LDS (wave-local tile; per-wave DS ops are in-order: no barrier) ----
        #pragma unroll
        for (int t = 0; t < 4; ++t) {
            #pragma unroll
            for (int r = 0; r < 4; ++r)
                Pl[w][g * 4 + r][t * 16 + c] = (_Float16)pv[t][r];
        }

        // ---- O += P V  (Vt read applies the same column XOR; bits>=4 only) ----
        f16x8 af0 = *(const f16x8*)&Pl[w][c][g * 8];
        f16x8 af1 = *(const f16x8*)&Pl[w][c][32 + g * 8];
        #pragma unroll
        for (int t = 0; t < 4; ++t) {
            int cv0 = (g * 8)      ^ ((t & 3) << 4);
            int cv1 = (32 + g * 8) ^ ((t & 3) << 4);
            f16x8 b0 = *(const f16x8*)&Vt[t * 16 + c][cv0];
            f16x8 b1 = *(const f16x8*)&Vt[t * 16 + c][cv1];
            oacc[t] = __builtin_amdgcn_mfma_f32_16x16x32_f16(af0, b0, oacc[t], 0, 0, 0);
            oacc[t] = __builtin_amdgcn_mfma_f32_16x16x32_f16(af1, b1, oacc[t], 0, 0, 0);
        }
    }

    // ---- epilogue: O / l ----
    float* orow = O + ((size_t)b * Sn + (size_t)nb * 64 + w * 16) * HD + h * Dn;
    #pragma unroll
    for (int r = 0; r < 4; ++r) {
        float inv = 1.0f / l[r];
        #pragma unroll
        for (int t = 0; t < 4; ++t)
            orow[(size_t)(g * 4 + r) * HD + t * 16 + c] = oacc[t][r] * inv;
    }
}

extern "C" void kernel_launch(void* const* d_in, const int* in_sizes, int n_in,
                              void* d_out, int out_size, void* d_ws, size_t ws_size,
                              hipStream_t stream) {
    const float* Q = (const float*)d_in[0];
    const float* K = (const float*)d_in[1];
    const float* V = (const float*)d_in[2];
    float* O = (float*)d_out;

    float* qpool = (float*)d_ws;                      // 131072 f32
    float* kpool = qpool + (size_t)Bn * Hh * NB * Dn; // 131072 f32
    int*   topk  = (int*)(kpool + (size_t)Bn * Hh * NB * Dn); // 2048*7 int

    dim3 grid(Bn * Hh * NB);
    sla_pool<<<grid, 64, 0, stream>>>(Q, K, qpool, kpool);
    sla_topk<<<grid, 64, 0, stream>>>(qpool, kpool, topk);
    sla_attn<<<grid, 256, 0, stream>>>(Q, K, V, topk, O);
}

// Round 3
// 73.588 us; speedup vs baseline: 1.3855x; 1.2002x over previous
//
#include <hip/hip_runtime.h>

constexpr int Bn = 2;
constexpr int Sn = 4096;
constexpr int Hh = 16;
constexpr int Dn = 64;
constexpr int HD = 1024;   // Hh * Dn
constexpr int NB = 64;     // Sn / 64
constexpr int KS = 7;      // ceil(0.1 * NB)

typedef _Float16 f16x8 __attribute__((ext_vector_type(8)));
typedef _Float16 f16x4 __attribute__((ext_vector_type(4)));
typedef float    f32x4 __attribute__((ext_vector_type(4)));

static __device__ __forceinline__ f16x4 cvt4(float4 v) {
    f16x4 r;
    r[0] = (_Float16)v.x; r[1] = (_Float16)v.y;
    r[2] = (_Float16)v.z; r[3] = (_Float16)v.w;
    return r;
}
static __device__ __forceinline__ f16x8 cvt8(float4 a, float4 b) {
    f16x8 r;
    r[0] = (_Float16)a.x; r[1] = (_Float16)a.y;
    r[2] = (_Float16)a.z; r[3] = (_Float16)a.w;
    r[4] = (_Float16)b.x; r[5] = (_Float16)b.y;
    r[6] = (_Float16)b.z; r[7] = (_Float16)b.w;
    return r;
}

// ---------------- kernel 1: per-block mean pooling of Q and K ----------------
__global__ __launch_bounds__(64) void sla_pool(const float* __restrict__ Q,
                                               const float* __restrict__ K,
                                               float* __restrict__ qpool,
                                               float* __restrict__ kpool) {
    int bid = blockIdx.x;                 // (b*Hh + h)*NB + nb
    int b   = bid / (Hh * NB);
    int rem = bid % (Hh * NB);
    int h   = rem / NB;
    int nb  = rem % NB;
    int d   = threadIdx.x;

    const float* qp = Q + ((size_t)b * Sn + (size_t)nb * 64) * HD + h * Dn + d;
    const float* kp = K + ((size_t)b * Sn + (size_t)nb * 64) * HD + h * Dn + d;
    double sq = 0.0, sk = 0.0;
    #pragma unroll 16
    for (int r = 0; r < 64; ++r) {
        sq += (double)qp[(size_t)r * HD];
        sk += (double)kp[(size_t)r * HD];
    }
    qpool[(size_t)bid * 64 + d] = (float)(sq * (1.0 / 64.0));
    kpool[(size_t)bid * 64 + d] = (float)(sk * (1.0 / 64.0));
}

// -------- kernel 2: block scores (fp64) + top-7 selection (lax.top_k ties: lower idx) --------
__global__ __launch_bounds__(64) void sla_topk(const float* __restrict__ qpool,
                                               const float* __restrict__ kpool,
                                               int* __restrict__ topk) {
    int bid = blockIdx.x;                 // (b*Hh + h)*NB + nb
    int bh  = bid / NB;
    int j   = threadIdx.x;                // candidate key block

    const float* qp = qpool + (size_t)bid * 64;
    const float* kp = kpool + ((size_t)bh * NB + j) * 64;
    double s = 0.0;
    #pragma unroll 8
    for (int d = 0; d < 64; ++d) s += (double)qp[d] * (double)kp[d];

    double v  = s;
    int   idx = j;
    #pragma unroll
    for (int it = 0; it < KS; ++it) {
        double bv = v; int bi = idx;
        #pragma unroll
        for (int off = 1; off < 64; off <<= 1) {
            double ov = __shfl_xor(bv, off);
            int    oi = __shfl_xor(bi, off);
            if (ov > bv || (ov == bv && oi < bi)) { bv = ov; bi = oi; }
        }
        if (j == 0) topk[(size_t)bid * KS + it] = bi;
        if (idx == bi) v = -1e300;        // knock out the winner
    }
}

// ---------------- kernel 3: sparse flash attention over selected blocks ----------------
// Swapped-operand scheme: S^T = mfma(K,Q) puts a full q-row's scores in-lane
// (col=q=lane&15, row=key); softmax stats are per-lane scalars; O^T = mfma(Vt,Pt)
// needs no stat broadcast and stores as float4 rows.
__global__ __launch_bounds__(256) void sla_attn(const float* __restrict__ Q,
                                                const float* __restrict__ K,
                                                const float* __restrict__ V,
                                                const int* __restrict__ topk,
                                                float* __restrict__ O) {
    __shared__ _Float16 Ks[64][64];       // [key][d], 8-elem chunks XOR-swizzled by key&7
    __shared__ _Float16 Vt[64][72];       // [d][key^swz] transposed + XOR-swizzled cols
    __shared__ _Float16 Pq[4][16][68];    // per-wave P^T as [q][key] (write b64, read b128)

    // XCD-chunked swizzle: 2048 WGs = 8 XCDs x 256; consecutive logical bids
    // (same b,h -> shared K/V working set, ~2MB < 4MB XCD L2) stay on one XCD.
    int raw = blockIdx.x;
    int bid = (raw & 7) * 256 + (raw >> 3);

    int b   = bid / (Hh * NB);
    int rem = bid % (Hh * NB);
    int h   = rem / NB;
    int nb  = rem % NB;

    int tid  = threadIdx.x;
    int w    = tid >> 6;                  // wave id: q rows [w*16, w*16+16)
    int lane = tid & 63;
    int c    = lane & 15;                 // q row within wave / key row within tile
    int g    = lane >> 4;                 // fragment k-group

    int skey = tid >> 2;                  // staging: key row (0..63 across WG)
    int sd3  = tid & 3;                   // staging: d-group selector
    int sdg  = sd3 << 4;                  // staging: d base (16 elements)
    int vcol = skey ^ (sd3 << 4);         // Vt swizzled write column
    int kch0 = ((sd3 << 1) + 0) ^ (skey & 7);  // Ks swizzled chunk for d sdg..sdg+7
    int kch1 = ((sd3 << 1) + 1) ^ (skey & 7);  // Ks swizzled chunk for d sdg+8..sdg+15
    int rch0 = (g + 0) ^ (c & 7);         // Ks read chunk, s2=0
    int rch1 = (g + 4) ^ (c & 7);         // Ks read chunk, s2=1

    // ---- hoist all 7 selected block indices (uniform -> scalar loads) ----
    int jidx[KS];
    {
        const int* tkp = topk + (size_t)bid * KS;
        #pragma unroll
        for (int i = 0; i < KS; ++i) jidx[i] = tkp[i];
    }

    // ---- Q fragments, scale 1/8 folded (exact in fp16) ----
    f16x8 qf[2];
    {
        const float* qrow = Q + ((size_t)b * Sn + (size_t)nb * 64 + w * 16 + c) * HD + h * Dn;
        #pragma unroll
        for (int s2 = 0; s2 < 2; ++s2) {
            float4 a0 = *(const float4*)(qrow + s2 * 32 + g * 8);
            float4 a1 = *(const float4*)(qrow + s2 * 32 + g * 8 + 4);
            f16x8 q;
            q[0] = (_Float16)(a0.x * 0.125f); q[1] = (_Float16)(a0.y * 0.125f);
            q[2] = (_Float16)(a0.z * 0.125f); q[3] = (_Float16)(a0.w * 0.125f);
            q[4] = (_Float16)(a1.x * 0.125f); q[5] = (_Float16)(a1.y * 0.125f);
            q[6] = (_Float16)(a1.z * 0.125f); q[7] = (_Float16)(a1.w * 0.125f);
            qf[s2] = q;
        }
    }

    float m = -1e30f, l = 0.f;            // per-lane scalars (q = c)
    f32x4 oacc[4];                        // O^T: d = 16t + 4g + r, q = c
    #pragma unroll
    for (int t = 0; t < 4; ++t) oacc[t] = f32x4{0.f, 0.f, 0.f, 0.f};

    const float* kbase = K + (size_t)b * Sn * HD + h * Dn;
    const float* vbase = V + (size_t)b * Sn * HD + h * Dn;

    // ---- prologue: prefetch block 0 into registers ----
    float4 kx[4], vx[4];
    {
        const float* kp = kbase + ((size_t)jidx[0] * 64 + skey) * HD + sdg;
        const float* vp = vbase + ((size_t)jidx[0] * 64 + skey) * HD + sdg;
        #pragma unroll
        for (int i = 0; i < 4; ++i) kx[i] = *(const float4*)(kp + i * 4);
        #pragma unroll
        for (int i = 0; i < 4; ++i) vx[i] = *(const float4*)(vp + i * 4);
    }

    for (int kb = 0; kb < KS; ++kb) {
        __syncthreads();                  // previous iter's MFMA reads of Ks/Vt done
        // ---- STAGE_WRITE: regs -> LDS ----
        *(f16x8*)&Ks[skey][kch0 * 8] = cvt8(kx[0], kx[1]);
        *(f16x8*)&Ks[skey][kch1 * 8] = cvt8(kx[2], kx[3]);
        #pragma unroll
        for (int i = 0; i < 4; ++i) {
            float4 v = vx[i];
            int db = sdg + i * 4;
            Vt[db + 0][vcol] = (_Float16)v.x;
            Vt[db + 1][vcol] = (_Float16)v.y;
            Vt[db + 2][vcol] = (_Float16)v.z;
            Vt[db + 3][vcol] = (_Float16)v.w;
        }
        // ---- PREFETCH next block into registers (overlaps barrier + compute) ----
        if (kb + 1 < KS) {
            const float* kp = kbase + ((size_t)jidx[kb + 1] * 64 + skey) * HD + sdg;
            const float* vp = vbase + ((size_t)jidx[kb + 1] * 64 + skey) * HD + sdg;
            #pragma unroll
            for (int i = 0; i < 4; ++i) kx[i] = *(const float4*)(kp + i * 4);
            #pragma unroll
            for (int i = 0; i < 4; ++i) vx[i] = *(const float4*)(vp + i * 4);
        }
        __syncthreads();                  // staging visible to all waves

        // ---- S^T = K (Q/8)^T : rows=key(16t+4g+r), col=q(c) ----
        f32x4 sacc[4];
        #pragma unroll
        for (int t = 0; t < 4; ++t) sacc[t] = f32x4{0.f, 0.f, 0.f, 0.f};
        #pragma unroll
        for (int t = 0; t < 4; ++t) {
            f16x8 a0 = *(const f16x8*)&Ks[t * 16 + c][rch0 * 8];
            f16x8 a1 = *(const f16x8*)&Ks[t * 16 + c][rch1 * 8];
            sacc[t] = __builtin_amdgcn_mfma_f32_16x16x32_f16(a0, qf[0], sacc[t], 0, 0, 0);
            sacc[t] = __builtin_amdgcn_mfma_f32_16x16x32_f16(a1, qf[1], sacc[t], 0, 0, 0);
        }

        // ---- online softmax: whole q-row is in-lane (16 vals) + lanes c, c+16, c+32, c+48 ----
        float pm;
        {
            float m0 = fmaxf(fmaxf(sacc[0][0], sacc[0][1]), fmaxf(sacc[0][2], sacc[0][3]));
            float m1 = fmaxf(fmaxf(sacc[1][0], sacc[1][1]), fmaxf(sacc[1][2], sacc[1][3]));
            float m2 = fmaxf(fmaxf(sacc[2][0], sacc[2][1]), fmaxf(sacc[2][2], sacc[2][3]));
            float m3 = fmaxf(fmaxf(sacc[3][0], sacc[3][1]), fmaxf(sacc[3][2], sacc[3][3]));
            pm = fmaxf(fmaxf(m0, m1), fmaxf(m2, m3));
        }
        pm = fmaxf(pm, __shfl_xor(pm, 16));
        pm = fmaxf(pm, __shfl_xor(pm, 32));

        float mn = fmaxf(m, pm);
        float al = __expf(m - mn);
        m = mn;

        float e[4][4];
        float rs = 0.f;
        #pragma unroll
        for (int t = 0; t < 4; ++t) {
            #pragma unroll
            for (int r = 0; r < 4; ++r) {
                float x = __expf(sacc[t][r] - m);
                e[t][r] = x;
                rs += x;
            }
        }
        rs += __shfl_xor(rs, 16);
        rs += __shfl_xor(rs, 32);
        l = l * al + rs;
        #pragma unroll
        for (int t = 0; t < 4; ++t) {
            oacc[t][0] *= al; oacc[t][1] *= al;
            oacc[t][2] *= al; oacc[t][3] *= al;
        }

        // ---- P^T -> Pq (wave-local, in-order DS: no barrier) ----
        #pragma unroll
        for (int t = 0; t < 4; ++t) {
            f16x4 p4;
            p4[0] = (_Float16)e[t][0]; p4[1] = (_Float16)e[t][1];
            p4[2] = (_Float16)e[t][2]; p4[3] = (_Float16)e[t][3];
            *(f16x4*)&Pq[w][c][t * 16 + g * 4] = p4;
        }

        // ---- O^T += V^T P^T ----
        #pragma unroll
        for (int t = 0; t < 4; ++t) {
            int cv0 = (g * 8)      ^ ((t & 3) << 4);
            int cv1 = (32 + g * 8) ^ ((t & 3) << 4);
            f16x8 va0 = *(const f16x8*)&Vt[t * 16 + c][cv0];
            f16x8 va1 = *(const f16x8*)&Vt[t * 16 + c][cv1];
            f16x8 pa0 = *(const f16x8*)&Pq[w][c][g * 8];
            f16x8 pa1 = *(const f16x8*)&Pq[w][c][32 + g * 8];
            oacc[t] = __builtin_amdgcn_mfma_f32_16x16x32_f16(va0, pa0, oacc[t], 0, 0, 0);
            oacc[t] = __builtin_amdgcn_mfma_f32_16x16x32_f16(va1, pa1, oacc[t], 0, 0, 0);
        }
    }

    // ---- epilogue: O[q][d] = O^T / l, one float4 per d-tile ----
    float inv = 1.0f / l;
    float* orow = O + ((size_t)b * Sn + (size_t)nb * 64 + w * 16 + c) * HD + h * Dn;
    #pragma unroll
    for (int t = 0; t < 4; ++t) {
        float4 o4;
        o4.x = oacc[t][0] * inv; o4.y = oacc[t][1] * inv;
        o4.z = oacc[t][2] * inv; o4.w = oacc[t][3] * inv;
        *(float4*)(orow + t * 16 + g * 4) = o4;
    }
}

extern "C" void kernel_launch(void* const* d_in, const int* in_sizes, int n_in,
                              void* d_out, int out_size, void* d_ws, size_t ws_size,
                              hipStream_t stream) {
    const float* Q = (const float*)d_in[0];
    const float* K = (const float*)d_in[1];
    const float* V = (const float*)d_in[2];
    float* O = (float*)d_out;

    float* qpool = (float*)d_ws;                      // 131072 f32
    float* kpool = qpool + (size_t)Bn * Hh * NB * Dn; // 131072 f32
    int*   topk  = (int*)(kpool + (size_t)Bn * Hh * NB * Dn); // 2048*7 int

    dim3 grid(Bn * Hh * NB);
    sla_pool<<<grid, 64, 0, stream>>>(Q, K, qpool, kpool);
    sla_topk<<<grid, 64, 0, stream>>>(qpool, kpool, topk);
    sla_attn<<<grid, 256, 0, stream>>>(Q, K, V, topk, O);
}